// Round 1
// baseline (94.699 us; speedup 1.0000x reference)
//
#include <hip/hip_runtime.h>

// SparseConv1D on MI355X, round 8.
// out[b,o,l] = sum_{t,i} W[o,i,t] * x[b,i,l+tap_t] = 32 shifted GEMMs (MFMA 16x16x32 bf16).
// R8 vs R7 (R7 and 5 prior restructures all flat ~90-93us; sconv latency-bound ~4-5x above
// its 8.3us MFMA floor; every prior variant was 1 block/CU => each __syncthreads drains
// vmcnt(0) for the WHOLE CU):
//  - Ring shrunk 1024->512 rows (128KB->64KB): l-tile 128 (32 tiles), window slides PER TAP
//    (live span = 128-row window + max jump 256 = 384 <= 512). Jumps >=128 stage only the
//    new 128-row window (gap rows skipped).
//  - Grid 512 blocks x 256 thr (4 waves: 2 lh x 2 ch), __launch_bounds__(256,2):
//    2 blocks/CU co-resident. Barrier drains of block A overlap block B's MFMAs.
//  - Per-tap barrier makes vmcnt(0) drains benign: everything outstanding at the barrier
//    (tap t+1 staging + tap t+1 W prefetch) is needed right after it. Breg lgkmcnt stays
//    counted and independent of the vmcnt stream.
//  - W path (global->reg, frag-major, dbuf), swizzle, bank-uniform ds_read_b128 unchanged.

#define B_    16
#define CIN   64
#define COUT  64
#define LEN   4096
#define PAD_LO 512
#define PAD_HI 256
#define LPAD  (LEN + PAD_LO + PAD_HI)   // 4864
#define NTAP  32

typedef float f32x4 __attribute__((ext_vector_type(4)));
typedef short bf16x8_s __attribute__((ext_vector_type(8)));
typedef __bf16 bf16x8_b __attribute__((ext_vector_type(8)));
typedef unsigned short u16x8 __attribute__((ext_vector_type(8)));

template <typename V>
static __device__ inline auto mfma_16x16x32_bf16(V a, V b, f32x4 c, int)
    -> decltype(__builtin_amdgcn_mfma_f32_16x16x32_bf16(a, b, c, 0, 0, 0)) {
  return __builtin_amdgcn_mfma_f32_16x16x32_bf16(a, b, c, 0, 0, 0);
}
template <typename V>
static __device__ inline f32x4 mfma_16x16x32_bf16(V a, V b, f32x4 c, long) {
  return __builtin_amdgcn_mfma_f32_16x16x32_bf16(
      __builtin_bit_cast(bf16x8_b, a), __builtin_bit_cast(bf16x8_b, b), c, 0, 0, 0);
}

static __device__ inline unsigned short f32_to_bf16_rne(float f) {
  unsigned int u = __builtin_bit_cast(unsigned int, f);
  u += 0x7fffu + ((u >> 16) & 1u);
  return (unsigned short)(u >> 16);
}

// async 16B/lane global->LDS; lds dest is the wave-uniform base (HW adds lane*16)
static __device__ inline void async_copy16(const void* g, void* l) {
  __builtin_amdgcn_global_load_lds((const __attribute__((address_space(1))) unsigned int*)g,
                                   (__attribute__((address_space(3))) unsigned int*)l, 16, 0, 0);
}

// ---- fused prep: x[b][i][l] f32 -> Xp[b][lp][i] bf16 (padded); pad-blocks also do
// ---- w[o][i][t] f32 -> Wf[t][c][m][lane][8] bf16 (frag-major, 8KB/tap)
__global__ __launch_bounds__(256) void prep_xw(const float* __restrict__ x,
                                               const float* __restrict__ w,
                                               unsigned short* __restrict__ xp,
                                               unsigned short* __restrict__ wf) {
  __shared__ float tile[64][65];
  const int b = blockIdx.y;
  const int lp0 = blockIdx.x * 64;
  const int tid = threadIdx.x;
  const bool data = (lp0 >= PAD_LO) && (lp0 < PAD_LO + LEN);
  if (data) {
    const int l0 = lp0 - PAD_LO;
#pragma unroll
    for (int it = 0; it < 4; ++it) {
      const int pidx = it * 256 + tid;
      const int il = pidx >> 4;
      const int lq = (pidx & 15) * 4;
      const float4 v = *(const float4*)&x[(size_t)(b * CIN + il) * LEN + l0 + lq];
      tile[lq + 0][il] = v.x;
      tile[lq + 1][il] = v.y;
      tile[lq + 2][il] = v.z;
      tile[lq + 3][il] = v.w;
    }
  } else if (lp0 < PAD_LO) {
    // pad block: also transpose a 1/128 slice of W (16 b * 8 x-blocks = 128 slices)
    const int base = (b * 8 + blockIdx.x) * 1024;
#pragma unroll
    for (int it = 0; it < 4; ++it) {
      const int e = base + it * 256 + tid;   // < 131072
      const int j = e & 7;
      const int lane = (e >> 3) & 63;
      const int m = (e >> 9) & 3;
      const int c = (e >> 11) & 1;
      const int t = e >> 12;
      const int o = m * 16 + (lane & 15);
      const int i = c * 32 + (lane >> 4) * 8 + j;
      wf[e] = f32_to_bf16_rne(w[(size_t)(o * CIN + i) * NTAP + t]);
    }
  }
  __syncthreads();
#pragma unroll
  for (int it = 0; it < 2; ++it) {
    const int pidx = it * 256 + tid;
    const int ll = pidx >> 3;
    const int i8 = (pidx & 7) * 8;
    u16x8 v = {0, 0, 0, 0, 0, 0, 0, 0};
    if (data) {
#pragma unroll
      for (int j = 0; j < 8; ++j) v[j] = f32_to_bf16_rne(tile[ll][i8 + j]);
    }
    *(u16x8*)&xp[(size_t)(b * LPAD + lp0 + ll) * CIN + i8] = v;
  }
}

// ------- main: 2 blocks/CU, per-tap sliding 512-row ring, W global->reg dbuf ----------
__global__ __launch_bounds__(256, 2) void sconv_main(const unsigned short* __restrict__ xp,
                                                     const unsigned short* __restrict__ wf,
                                                     float* __restrict__ out) {
  constexpr int TAP[NTAP] = {-512, -256, -128, -96, -64, -48, -32, -24, -16, -12, -8,
                             -6,   -4,   -3,   -2,  -1,  0,   1,   2,   3,   4,  6,
                             8,    12,   16,   24,  32,  48,  64,  96,  128, 256};
  __shared__ alignas(16) char smem[65536];   // ring: 512 rows x 128B

  const int id = blockIdx.x;                  // 512 blocks = 16 b x 32 l-tiles
  const int b = (id & 7) * 2 + (id >> 8);     // XCD k <- batches {2k, 2k+1}
  const int l0 = ((id >> 3) & 31) * 128;      // 32 l-tiles of 128
  const int lb = l0 + PAD_LO;                 // absolute padded base row (mult of 128)
  const int tid = threadIdx.x;
  const int wv = tid >> 6, lane = tid & 63;
  const int q = lane >> 4, r = lane & 15;
  const int lh = wv >> 1, ch = wv & 1;        // wave: l-half (64 l), i-half (32 i)

  const char* xbase = (const char*)xp + ((size_t)b * LPAD + lb) * (CIN * 2);
  const char* wbase = (const char*)wf;

  // stage relative rows [a0, a0+8*ng) into ring; a0 8-aligned.
  // LDS[slot][c'] = G[row][c' ^ (row&7)]
  auto stageB = [&](int a0, int ng) {
    for (int g = wv; g < ng; g += 4) {
      const int ra = a0 + g * 8 + (lane >> 3);
      const int cs = (lane & 7) ^ (ra & 7);
      const int sb = (lb + a0 + g * 8) & 511;  // 8-aligned group, never wraps
      async_copy16(xbase + (ptrdiff_t)ra * 128 + cs * 16, smem + sb * 128);
    }
  };

  bf16x8_s Wreg[2][4], Breg[4];
  f32x4 acc[4][4] = {};

  auto loadW = [&](int tt, int p) {            // global, frag-major, coalesced
    const char* src = wbase + tt * 8192 + ch * 4096 + lane * 16;
#pragma unroll
    for (int m = 0; m < 4; ++m)
      Wreg[p][m] = *(const bf16x8_s*)(src + m * 1024);
  };
  auto readB = [&](int tt) {
    const int e = (TAP[tt] + r) & 7;           // row&7 for this lane's B rows
#pragma unroll
    for (int n = 0; n < 4; ++n) {
      const int slot = (lb + TAP[tt] + lh * 64 + 16 * n + r) & 511;
      Breg[n] = *(const bf16x8_s*)(smem + slot * 128 + (((ch * 4 + q) ^ e) << 4));
    }
  };

  // prologue: W(0) to regs; ring rows = window(0) = [-512, -385]
  loadW(0, 0);
  stageB(TAP[0], 16);

#pragma unroll
  for (int t = 0; t < NTAP; ++t) {
    const int p = t & 1;
    __syncthreads();                           // window(t) resident; drains stage+W prefetch
    readB(t);                                  // lgkmcnt-counted, independent of vmcnt
    if (t + 1 < NTAP) {
      // stage window(t+1) \ window(t): for jumps >=128 stage only the new 128-row window
      const int lo = (TAP[t] + 128 > TAP[t + 1]) ? (TAP[t] + 128) : TAP[t + 1];
      const int a0 = lo & ~7;                  // <=7 identical-rewrite rows: benign
      const int ng = (TAP[t + 1] + 128 - a0 + 7) >> 3;
      stageB(a0, ng);                          // live span <= 384 < 512: WAR-safe
      loadW(t + 1, p ^ 1);                     // consumed after next barrier's vmcnt(0)
    }
    __builtin_amdgcn_sched_barrier(0);         // pin staging/prefetch issue above compute
#pragma unroll
    for (int m = 0; m < 4; ++m)
#pragma unroll
      for (int n = 0; n < 4; ++n)
        acc[m][n] = mfma_16x16x32_bf16(Wreg[p][m], Breg[n], acc[m][n], 0);
  }

  // ---- reduce the two i-halves through LDS (ring is dead now) ----
  __syncthreads();
  if (ch == 1) {
#pragma unroll
    for (int m = 0; m < 4; ++m)
#pragma unroll
      for (int n = 0; n < 4; ++n)
        *(f32x4*)(smem + lh * 16384 + ((m * 4 + n) * 64 + lane) * 16) = acc[m][n];
  }
  __syncthreads();
  if (ch == 0) {
#pragma unroll
    for (int m = 0; m < 4; ++m)
#pragma unroll
      for (int n = 0; n < 4; ++n) {
        const f32x4 other = *(const f32x4*)(smem + lh * 16384 + ((m * 4 + n) * 64 + lane) * 16);
        const f32x4 v = acc[m][n] + other;
        // C/D layout (verified): col(l) = lane&15, row(o) = (lane>>4)*4 + reg
#pragma unroll
        for (int d = 0; d < 4; ++d) {
          const int o = 16 * m + 4 * q + d;
          const int l = l0 + lh * 64 + 16 * n + r;
          out[((size_t)b * COUT + o) * LEN + l] = v[d];
        }
      }
  }
}

extern "C" void kernel_launch(void* const* d_in, const int* in_sizes, int n_in,
                              void* d_out, int out_size, void* d_ws, size_t ws_size,
                              hipStream_t stream) {
  const float* x = (const float*)d_in[0];        // [16][64][4096]
  const float* w = (const float*)d_in[1];        // [64][64][32]
  float* out = (float*)d_out;                    // [16][64][4096]

  unsigned short* xp = (unsigned short*)d_ws;                    // 16*4864*64 bf16 = 9.96 MB
  unsigned short* wfp = xp + (size_t)B_ * LPAD * CIN;            // 256 KB

  prep_xw<<<dim3(LPAD / 64, B_), 256, 0, stream>>>(x, w, xp, wfp);
  sconv_main<<<dim3(512), 256, 0, stream>>>(xp, wfp, out);
}

// Round 2
// 88.934 us; speedup vs baseline: 1.0648x; 1.0648x over previous
//
#include <hip/hip_runtime.h>

// SparseConv1D on MI355X, round 9.
// out[b,o,l] = sum_{t,i} W[o,i,t] * x[b,i,l+tap_t] = 32 shifted GEMMs (MFMA 16x16x32 bf16).
// R9 vs R8 (R8's per-tap barriers + 2 blocks/CU REGRESSED 90->94.7; root cause of 6 flat
// rounds = cooperative-staging barrier INSIDE the tap loop, each draining vmcnt(0)):
//  - ZERO barriers in the tap loop. Union of all 32 tap windows for a 256-col l-tile is
//    rows [-512,512) = 1024 x 128B = 128KB -> fits LDS. Stage ONCE in prologue, ONE
//    __syncthreads, then 32 taps of pure {prefetch W+B, 16 MFMA}.
//  - W dbuf via compiler-counted vmcnt (only vmem in loop = 4 W loads/tap -> vmcnt(4),
//    never 0). B dbuf via lgkmcnt. No dynamic staging counts anywhere.
//  - 256 blocks (16 b x 16 l-tiles) = exactly 1 block/CU; 8 waves (4 lh x 2 ch) =
//    2 waves/SIMD. MFMA floor/CU = 620 cyc/tap > LDS-read 384 cyc/tap -> MFMA-bound.
//  - prep regridded 1D so XCD k preps batches {2k,2k+1} = what its sconv blocks read:
//    stage burst hits local L2, not L3.

#define B_    16
#define CIN   64
#define COUT  64
#define LEN   4096
#define PAD_LO 512
#define PAD_HI 256
#define LPAD  (LEN + PAD_LO + PAD_HI)   // 4864
#define NTAP  32

typedef float f32x4 __attribute__((ext_vector_type(4)));
typedef short bf16x8_s __attribute__((ext_vector_type(8)));
typedef __bf16 bf16x8_b __attribute__((ext_vector_type(8)));
typedef unsigned short u16x8 __attribute__((ext_vector_type(8)));

template <typename V>
static __device__ inline auto mfma_16x16x32_bf16(V a, V b, f32x4 c, int)
    -> decltype(__builtin_amdgcn_mfma_f32_16x16x32_bf16(a, b, c, 0, 0, 0)) {
  return __builtin_amdgcn_mfma_f32_16x16x32_bf16(a, b, c, 0, 0, 0);
}
template <typename V>
static __device__ inline f32x4 mfma_16x16x32_bf16(V a, V b, f32x4 c, long) {
  return __builtin_amdgcn_mfma_f32_16x16x32_bf16(
      __builtin_bit_cast(bf16x8_b, a), __builtin_bit_cast(bf16x8_b, b), c, 0, 0, 0);
}

static __device__ inline unsigned short f32_to_bf16_rne(float f) {
  unsigned int u = __builtin_bit_cast(unsigned int, f);
  u += 0x7fffu + ((u >> 16) & 1u);
  return (unsigned short)(u >> 16);
}

// async 16B/lane global->LDS; lds dest is the wave-uniform base (HW adds lane*16)
static __device__ inline void async_copy16(const void* g, void* l) {
  __builtin_amdgcn_global_load_lds((const __attribute__((address_space(1))) unsigned int*)g,
                                   (__attribute__((address_space(3))) unsigned int*)l, 16, 0, 0);
}

// ---- fused prep: x[b][i][l] f32 -> Xp[b][lp][i] bf16 (padded); pad-blocks also do
// ---- w[o][i][t] f32 -> Wf[t][c][m][lane][8] bf16 (frag-major, 8KB/tap)
// 1D grid 1216 = 76 xt x 16 b; b chosen so XCD k (id&7) writes batches {2k,2k+1},
// matching sconv's consumer mapping (stage reads become local-L2 hits).
__global__ __launch_bounds__(256) void prep_xw(const float* __restrict__ x,
                                               const float* __restrict__ w,
                                               unsigned short* __restrict__ xp,
                                               unsigned short* __restrict__ wf) {
  __shared__ float tile[64][65];
  const int id = blockIdx.x;
  const int b = 2 * (id & 7) + ((id >> 3) & 1);
  const int xt = id >> 4;                  // [0,76)
  const int lp0 = xt * 64;
  const int tid = threadIdx.x;
  const bool data = (lp0 >= PAD_LO) && (lp0 < PAD_LO + LEN);
  if (data) {
    const int l0 = lp0 - PAD_LO;
#pragma unroll
    for (int it = 0; it < 4; ++it) {
      const int pidx = it * 256 + tid;
      const int il = pidx >> 4;
      const int lq = (pidx & 15) * 4;
      const float4 v = *(const float4*)&x[(size_t)(b * CIN + il) * LEN + l0 + lq];
      tile[lq + 0][il] = v.x;
      tile[lq + 1][il] = v.y;
      tile[lq + 2][il] = v.z;
      tile[lq + 3][il] = v.w;
    }
  } else if (lp0 < PAD_LO) {
    // pad block: also transpose a 1/128 slice of W (16 b * 8 xt = 128 slices)
    const int base = (b * 8 + xt) * 1024;
#pragma unroll
    for (int it = 0; it < 4; ++it) {
      const int e = base + it * 256 + tid;   // < 131072
      const int j = e & 7;
      const int lane = (e >> 3) & 63;
      const int m = (e >> 9) & 3;
      const int c = (e >> 11) & 1;
      const int t = e >> 12;
      const int o = m * 16 + (lane & 15);
      const int i = c * 32 + (lane >> 4) * 8 + j;
      wf[e] = f32_to_bf16_rne(w[(size_t)(o * CIN + i) * NTAP + t]);
    }
  }
  __syncthreads();
#pragma unroll
  for (int it = 0; it < 2; ++it) {
    const int pidx = it * 256 + tid;
    const int ll = pidx >> 3;
    const int i8 = (pidx & 7) * 8;
    u16x8 v = {0, 0, 0, 0, 0, 0, 0, 0};
    if (data) {
#pragma unroll
      for (int j = 0; j < 8; ++j) v[j] = f32_to_bf16_rne(tile[ll][i8 + j]);
    }
    *(u16x8*)&xp[(size_t)(b * LPAD + lp0 + ll) * CIN + i8] = v;
  }
}

// ------- main: stage-once 128KB window, ONE barrier, barrier-free tap loop -----------
__global__ __launch_bounds__(512, 2) void sconv_main(const unsigned short* __restrict__ xp,
                                                     const unsigned short* __restrict__ wf,
                                                     float* __restrict__ out) {
  constexpr int TAP[NTAP] = {-512, -256, -128, -96, -64, -48, -32, -24, -16, -12, -8,
                             -6,   -4,   -3,   -2,  -1,  0,   1,   2,   3,   4,  6,
                             8,    12,   16,   24,  32,  48,  64,  96,  128, 256};
  __shared__ alignas(16) char smem[131072];   // 1024 rows x 128B, staged ONCE

  const int id = blockIdx.x;                  // 256 blocks = 16 b x 16 l-tiles
  const int b = (id & 7) * 2 + (id >> 7);     // XCD k <- batches {2k,2k+1}
  const int l0 = ((id >> 3) & 15) * 256;      // 16 l-tiles of 256
  const int lb = l0 + PAD_LO;                 // absolute padded base row (mult of 256)
  const int tid = threadIdx.x;
  const int wv = tid >> 6, lane = tid & 63;
  const int q = lane >> 4, r = lane & 15;
  const int lh = wv >> 1, ch = wv & 1;        // wave: l-quarter (64 l), i-half (32 i)

  const char* xbase = (const char*)xp + ((size_t)b * LPAD + lb) * (CIN * 2);
  const char* wbase = (const char*)wf;

  bf16x8_s Wreg[2][4], Breg[2][4];
  f32x4 acc[4][4] = {};

  auto loadW = [&](int tt, int p) {            // global, frag-major, coalesced, L2-hit
    const char* src = wbase + tt * 8192 + ch * 4096 + lane * 16;
#pragma unroll
    for (int m = 0; m < 4; ++m)
      Wreg[p][m] = *(const bf16x8_s*)(src + m * 1024);
  };
  // LDS[slot][c'] = G[row][c' ^ (row&7)]; lb==0 (mod 256) so row&7 == (TAP+r)&7
  auto readB = [&](int tt, int p) {
    const int e = (TAP[tt] + r) & 7;
#pragma unroll
    for (int n = 0; n < 4; ++n) {
      const int slot = (lb + TAP[tt] + lh * 64 + 16 * n + r) & 1023;
      Breg[p][n] = *(const bf16x8_s*)(smem + slot * 128 + (((ch * 4 + q) ^ e) << 4));
    }
  };

  // ---- prologue: stage the full window rows [-512, 512) (1024 rows, bijective slots) ----
#pragma unroll
  for (int i = 0; i < 16; ++i) {
    const int g = wv + i * 8;                  // 128 groups of 8 rows
    const int ra = -512 + g * 8 + (lane >> 3);
    const int cs = (lane & 7) ^ (ra & 7);
    const int sb = (lb - 512 + g * 8) & 1023;  // 8-aligned group, bijective over window
    async_copy16(xbase + (ptrdiff_t)ra * 128 + cs * 16, smem + sb * 128);
  }
  loadW(0, 0);
  __syncthreads();                             // the ONLY pre-epilogue barrier
  readB(0, 0);

  // ---- barrier-free tap loop: W via counted vmcnt, B via counted lgkmcnt ----
#pragma unroll
  for (int t = 0; t < NTAP; ++t) {
    const int p = t & 1;
    if (t + 1 < NTAP) {
      loadW(t + 1, p ^ 1);                     // vmcnt-counted, 2-deep dbuf
      readB(t + 1, p ^ 1);                     // lgkmcnt-counted, 2-deep dbuf
    }
    __builtin_amdgcn_sched_barrier(0);         // pin prefetch issue above this tap's MFMAs
#pragma unroll
    for (int m = 0; m < 4; ++m)
#pragma unroll
      for (int n = 0; n < 4; ++n)
        acc[m][n] = mfma_16x16x32_bf16(Wreg[p][m], Breg[p][n], acc[m][n], 0);
  }

  // ---- reduce the two i-halves through LDS (ring is dead now) ----
  __syncthreads();
  if (ch == 1) {
#pragma unroll
    for (int m = 0; m < 4; ++m)
#pragma unroll
      for (int n = 0; n < 4; ++n)
        *(f32x4*)(smem + lh * 16384 + ((m * 4 + n) * 64 + lane) * 16) = acc[m][n];
  }
  __syncthreads();
  if (ch == 0) {
#pragma unroll
    for (int m = 0; m < 4; ++m)
#pragma unroll
      for (int n = 0; n < 4; ++n) {
        const f32x4 other = *(const f32x4*)(smem + lh * 16384 + ((m * 4 + n) * 64 + lane) * 16);
        const f32x4 v = acc[m][n] + other;
        // C/D layout (verified): col(l) = lane&15, row(o) = (lane>>4)*4 + reg
#pragma unroll
        for (int d = 0; d < 4; ++d) {
          const int o = 16 * m + 4 * q + d;
          const int l = l0 + lh * 64 + 16 * n + r;
          out[((size_t)b * COUT + o) * LEN + l] = v[d];
        }
      }
  }
}

extern "C" void kernel_launch(void* const* d_in, const int* in_sizes, int n_in,
                              void* d_out, int out_size, void* d_ws, size_t ws_size,
                              hipStream_t stream) {
  const float* x = (const float*)d_in[0];        // [16][64][4096]
  const float* w = (const float*)d_in[1];        // [64][64][32]
  float* out = (float*)d_out;                    // [16][64][4096]

  unsigned short* xp = (unsigned short*)d_ws;                    // 16*4864*64 bf16 = 9.96 MB
  unsigned short* wfp = xp + (size_t)B_ * LPAD * CIN;            // 256 KB

  prep_xw<<<dim3((LPAD / 64) * B_), 256, 0, stream>>>(x, w, xp, wfp);
  sconv_main<<<dim3(256), 512, 0, stream>>>(xp, wfp, out);
}